// Round 1
// baseline (62.175 us; speedup 1.0000x reference)
//
#include <hip/hip_runtime.h>

// SSIM loss, fused single pass.
// inputs: img1, img2 float32 (16,3,512,512); output: float32 [16]
// Strategy: per (b,c,row-strip) block; vertical sliding 11-row column sums of
// {x1, x2, x1^2, x2^2, x1*x2} in registers (2 cols/thread), published to LDS
// per output row; horizontal 11-window per output pixel from LDS (b64 reads,
// pad-swizzled layout to kill stride-2 bank conflicts); SSIM per pixel;
// block reduce -> atomicAdd(double) -> tiny finalize kernel.

namespace {
constexpr int BATCH = 16;
constexpr int CHAN  = 3;
constexpr int HDIM  = 512;
constexpr int WDIM  = 512;
constexpr int WIN   = 11;
constexpr int HO    = HDIM - WIN + 1;   // 502
constexpr int WO    = WDIM - WIN + 1;   // 502
constexpr int NSTRIPS = 16;
constexpr int RPS   = (HO + NSTRIPS - 1) / NSTRIPS;  // 32
constexpr int NTHR  = 256;
constexpr float C1F = 6.5025f;    // (0.01*255)^2
constexpr float C2F = 58.5225f;   // (0.03*255)^2
constexpr float INVW2 = 1.0f / 121.0f;
// swizzled LDS array length: swz(511)+1+pad = 544
constexpr int VLEN = 544;
}

// pad 2 words every 32: breaks the (lane, lane+16) same-bank collision of the
// stride-2 float2 access pattern while keeping 8B alignment (pad is even).
__device__ __forceinline__ int swz(int x) { return x + 2 * (x >> 5); }

__device__ __forceinline__ float ssim_px(float v1, float v2, float v11,
                                         float v22, float v12) {
  float mu1 = v1 * INVW2, mu2 = v2 * INVW2;
  float mu1sq = mu1 * mu1, mu2sq = mu2 * mu2, mu12 = mu1 * mu2;
  float sig1 = fmaf(v11, INVW2, -mu1sq);
  float sig2 = fmaf(v22, INVW2, -mu2sq);
  float sg12 = fmaf(v12, INVW2, -mu12);
  float n = (2.0f * mu12 + C1F) * (2.0f * sg12 + C2F);
  float d = (mu1sq + mu2sq + C1F) * (sig1 + sig2 + C2F);
  return n / d;
}

__global__ __launch_bounds__(NTHR) void ssim_main(
    const float* __restrict__ g1, const float* __restrict__ g2,
    double* __restrict__ ws) {
  __shared__ float V0[VLEN], V1[VLEN], V2[VLEN], V3[VLEN], V4[VLEN];
  __shared__ float red[NTHR];

  const int bid   = blockIdx.x;
  const int strip = bid % NSTRIPS;
  const int bc    = bid / NSTRIPS;
  const int b     = bc / CHAN;
  const int c     = bc % CHAN;
  const int r0    = strip * RPS;
  const int r1    = min(r0 + RPS, HO);

  const int t  = threadIdx.x;
  const int x0 = 2 * t;                 // this thread's two columns
  const int w  = swz(x0);

  const float* __restrict__ p1 = g1 + (size_t)(b * CHAN + c) * HDIM * WDIM;
  const float* __restrict__ p2 = g2 + (size_t)(b * CHAN + c) * HDIM * WDIM;

  // vertical 11-row sliding sums for columns x0, x0+1 (registers)
  float a1x = 0, a1y = 0, a2x = 0, a2y = 0;
  float a11x = 0, a11y = 0, a22x = 0, a22y = 0, a12x = 0, a12y = 0;

#pragma unroll
  for (int dy = 0; dy < WIN; ++dy) {
    float2 u = *(const float2*)(p1 + (size_t)(r0 + dy) * WDIM + x0);
    float2 v = *(const float2*)(p2 + (size_t)(r0 + dy) * WDIM + x0);
    a1x += u.x;  a1y += u.y;
    a2x += v.x;  a2y += v.y;
    a11x = fmaf(u.x, u.x, a11x);  a11y = fmaf(u.y, u.y, a11y);
    a22x = fmaf(v.x, v.x, a22x);  a22y = fmaf(v.y, v.y, a22y);
    a12x = fmaf(u.x, v.x, a12x);  a12y = fmaf(u.y, v.y, a12y);
  }

  float acc = 0.0f;

  for (int r = r0; r < r1; ++r) {
    if (r > r0) {
      // slide: add input row r+10, subtract input row r-1
      float2 un = *(const float2*)(p1 + (size_t)(r + WIN - 1) * WDIM + x0);
      float2 vn = *(const float2*)(p2 + (size_t)(r + WIN - 1) * WDIM + x0);
      float2 uo = *(const float2*)(p1 + (size_t)(r - 1) * WDIM + x0);
      float2 vo = *(const float2*)(p2 + (size_t)(r - 1) * WDIM + x0);
      a1x += un.x - uo.x;  a1y += un.y - uo.y;
      a2x += vn.x - vo.x;  a2y += vn.y - vo.y;
      a11x += un.x * un.x - uo.x * uo.x;  a11y += un.y * un.y - uo.y * uo.y;
      a22x += vn.x * vn.x - vo.x * vo.x;  a22y += vn.y * vn.y - vo.y * vo.y;
      a12x += un.x * vn.x - uo.x * vo.x;  a12y += un.y * vn.y - uo.y * vo.y;
    }
    *(float2*)&V0[w] = make_float2(a1x, a1y);
    *(float2*)&V1[w] = make_float2(a2x, a2y);
    *(float2*)&V2[w] = make_float2(a11x, a11y);
    *(float2*)&V3[w] = make_float2(a22x, a22y);
    *(float2*)&V4[w] = make_float2(a12x, a12y);
    __syncthreads();

    if (x0 < WO) {  // x0 <= 500 -> both x0 and x0+1 are valid output cols
      float s1a, s1b, s2a, s2b, s11a, s11b, s22a, s22b, s12a, s12b;
      auto hsum = [&](const float* vq, float& S0, float& S1) {
        // window cols x0..x0+10 (S0) and x0+1..x0+11 (S1); pairs are
        // contiguous in the swizzled layout because x0+c is even.
        float2 q0 = *(const float2*)(vq + swz(x0 + 0));
        float2 q1 = *(const float2*)(vq + swz(x0 + 2));
        float2 q2 = *(const float2*)(vq + swz(x0 + 4));
        float2 q3 = *(const float2*)(vq + swz(x0 + 6));
        float2 q4 = *(const float2*)(vq + swz(x0 + 8));
        float2 q5 = *(const float2*)(vq + swz(x0 + 10));
        S0 = ((q0.x + q0.y) + (q1.x + q1.y)) +
             ((q2.x + q2.y) + (q3.x + q3.y)) + ((q4.x + q4.y) + q5.x);
        S1 = (S0 - q0.x) + q5.y;
      };
      hsum(V0, s1a, s1b);
      hsum(V1, s2a, s2b);
      hsum(V2, s11a, s11b);
      hsum(V3, s22a, s22b);
      hsum(V4, s12a, s12b);
      acc += ssim_px(s1a, s2a, s11a, s22a, s12a);
      acc += ssim_px(s1b, s2b, s11b, s22b, s12b);
    }
    __syncthreads();
  }

  // block reduction
  red[t] = acc;
  __syncthreads();
#pragma unroll
  for (int s = NTHR / 2; s > 0; s >>= 1) {
    if (t < s) red[t] += red[t + s];
    __syncthreads();
  }
  if (t == 0) atomicAdd(&ws[b], (double)red[0]);
}

__global__ void ssim_finalize(const double* __restrict__ ws,
                              float* __restrict__ out) {
  int i = threadIdx.x;
  if (i < BATCH) {
    double mean = ws[i] / ((double)CHAN * HO * WO);
    out[i] = (float)(1.0 - mean);
  }
}

extern "C" void kernel_launch(void* const* d_in, const int* in_sizes, int n_in,
                              void* d_out, int out_size, void* d_ws,
                              size_t ws_size, hipStream_t stream) {
  const float* img1 = (const float*)d_in[0];
  const float* img2 = (const float*)d_in[1];
  float* out = (float*)d_out;
  double* ws = (double*)d_ws;

  hipMemsetAsync(d_ws, 0, BATCH * sizeof(double), stream);
  ssim_main<<<dim3(BATCH * CHAN * NSTRIPS), NTHR, 0, stream>>>(img1, img2, ws);
  ssim_finalize<<<1, 64, 0, stream>>>(ws, out);
}